// Round 8
// baseline (164.263 us; speedup 1.0000x reference)
//
#include <hip/hip_runtime.h>

#define DD 160
#define HH 192
#define WW 160
#define HWs (HH * WW)          // 30720
#define NTOT 9830400.0f        // 2*160*192*160
#define DOUT 20                // output slices per block
#define NIT  28                // DOUT + 8 halo
#define NBLK 960               // 60 * 8 * 2

// ---- SD layout (f16): [buf 0..3][row 0..23][g 0..9][ch-slot 0..5], h4 units.
// Row stride 62; +2 per 8-row group; ch0..3 contiguous -> b128 write;
// ch4 at slot 4+(g&1).
#define SDRS 62
#define SDP  1492
// ---- HS layout (f16): [buf 0..3][ch 0..4][row 0..15][g 0..9], h4 units.
#define HSRS 10
#define HSC  162
#define HSP  810

typedef float    v4 __attribute__((ext_vector_type(4)));
typedef _Float16 h4 __attribute__((ext_vector_type(4)));
typedef _Float16 h2 __attribute__((ext_vector_type(2)));
typedef _Float16 h8 __attribute__((ext_vector_type(8)));

// LDS-only barrier: leaves global prefetch loads in flight.
__device__ __forceinline__ void block_sync_lds() {
    __builtin_amdgcn_s_waitcnt(0xc07f);   // vmcnt=63, expcnt=7, lgkmcnt=0
    __builtin_amdgcn_s_barrier();
}
__device__ __forceinline__ v4 up(h4 x) { return __builtin_convertvector(x, v4); }
__device__ __forceinline__ h4 dnp(v4 x) {
    h2 a = __builtin_bit_cast(h2, __builtin_amdgcn_cvt_pkrtz(x[0], x[1]));
    h2 b = __builtin_bit_cast(h2, __builtin_amdgcn_cvt_pkrtz(x[2], x[3]));
    return __builtin_shufflevector(a, b, 0, 1, 2, 3);
}

// Fully-fused NCC, D-first. TWO depth-slices per barrier interval (16
// intervals, 16 barriers -- r6 had 30), stacked wave roles (r6 mapping:
// every thread runs ph1 + one of ph2/ph3, giving 4-6 INDEPENDENT chains per
// wave per interval for ILP; r7 proved single-chain waves are latency-bound).
// Slice-indexed phases, 4-deep LDS buffers (idx s&3):
//   ph1(s): rolling 9-window D-sums in pure f32 (retiring slice re-read from
//           global: L2/L3-resident, bit-identical => exact cancellation);
//           writes f16 SD{s}. Interval k runs s=2k,2k+1 (k<=13).
//   ph2(s): 9-tap + 8-row slide H-sum over SD{s}, packed f16, initial rows
//           reg-kept -> HS{s}. Interval k runs s=2k-2,2k-1 (1<=k<=14).
//   ph3(s): sliding W-sum over HS{s} + cc -> acc. Interval k runs s=2k-4,
//           2k-3 (k>=6). Outputs s=8..27 -> depths d0..d0+19.
// Audit: SD{s} write@flr(s/2), read@+1, reuse@+2; HS{s} write@flr(s/2)+1,
// read@+2, reuse@+3 -- all barrier-separated.
// LDS 72.9 KB -> 2 blocks/CU; launch_bounds(256,2) relaxes VGPR cap.
__global__ __launch_bounds__(256, 2) void kf(const float* __restrict__ I,
                                             const float* __restrict__ J,
                                             float* __restrict__ partial) {
    __shared__ __align__(16) h4 SDL[4 * SDP];   // 47744 B
    __shared__ __align__(16) h4 HSL[4 * HSP];   // 25920 B
    __shared__ float red[256];                  //  1024 B

    const int tid = threadIdx.x;
    // XCD swizzle: 8 chunks of 120 consecutive linear tile ids.
    const int wgid = blockIdx.x;
    const int tl = (wgid & 7) * 120 + (wgid >> 3);
    const int bx = tl % 60, by = (tl / 60) % 8, b = tl / 480;
    const int w0 = (bx % 5) * 32, h0 = (bx / 5) * 16;
    const int d0 = by * DOUT;
    const int bid = tl;

    const int rt = tid ^ ((bx & 1) << 7);   // role swap waves 0,1 <-> 2,3

    // ---- ph1 decode: 240 columns = 24 rows x 10 f4-cols
    const bool p1 = rt < 240;
    const int r = rt / 10, g = rt % 10;
    const int gh = h0 - 4 + r, gw = w0 - 4 + g * 4;   // gw 16B-aligned
    const bool colOK = p1 && gh >= 0 && gh < HH && gw >= 0 && gw < WW;
    const size_t colOff = (size_t)gh * WW + gw;
    const float* Ib = I + (size_t)b * DD * HWs + colOff;
    const float* Jb = J + (size_t)b * DD * HWs + colOff;
    const int sdwOff = r * SDRS + (r >> 3) * 2 + 6 * g;

    // ---- ph2 decode: 100 tasks = 10 f4cols x 5 ch x 2 h-halves
    const bool p2 = rt < 100;
    const int g2 = rt % 10, ch2 = (rt / 10) % 5, hh0 = (rt / 50) * 8;
    const int sdrOff = hh0 * SDRS + (hh0 >> 3) * 2 + 6 * g2 +
                       (ch2 == 4 ? 4 + (g2 & 1) : ch2);
    const int hswOff = ch2 * HSC + hh0 * HSRS + g2;

    // ---- ph3 decode: 128 tasks = 16 h-rows x 8 w-segments of 4 outputs
    const bool p3 = rt >= 128;
    const int q3 = rt & 127;
    const int hh = q3 >> 3, sg = q3 & 7;
    const int hsrOff = hh * HSRS + sg;

    v4 sd0 = 0.f, sd1 = 0.f, sd2 = 0.f, sd3 = 0.f, sd4 = 0.f;
    // prefetch slots: slice parity 0/1 within interval (no dynamic indexing)
    v4 pLI0 = 0.f, pLJ0 = 0.f, pLI1 = 0.f, pLJ1 = 0.f;
    v4 pOI0 = 0.f, pOJ0 = 0.f, pOI1 = 0.f, pOJ1 = 0.f;
    float acc = 0.f;
    const float inv = 1.0f / 729.0f;

    {   // preload lead slices for s=0 (slot0) and s=1 (slot1)
        const int s0 = d0 - 4;
        if (colOK && s0 >= 0) {
            pLI0 = *(const v4*)(Ib + (size_t)s0 * HWs);
            pLJ0 = *(const v4*)(Jb + (size_t)s0 * HWs);
        }
        const int s1 = d0 - 3;
        if (colOK && s1 >= 0) {
            pLI1 = *(const v4*)(Ib + (size_t)s1 * HWs);
            pLJ1 = *(const v4*)(Jb + (size_t)s1 * HWs);
        }
    }

    // ph1 body for slice t; prefetches lead+retire for slice t+2 into the
    // same slots (t and t+2 share parity).
    auto PH1 = [&](int t, v4& pLIs, v4& pLJs, v4& pOIs, v4& pOJs) {
        const v4 cI = pLIs, cJ = pLJs;
        v4 dI = cI, dJv = cJ;
        v4 dII = cI * cI, dJJ = cJ * cJ, dIJ = cI * cJ;
        if (t >= 9) {       // retire slice t-9 via bit-identical re-read
            dI  -= pOIs;        dJv -= pOJs;
            dII -= pOIs * pOIs; dJJ -= pOJs * pOJs; dIJ -= pOIs * pOJs;
        }
        sd0 += dI; sd1 += dJv; sd2 += dII; sd3 += dJJ; sd4 += dIJ;
        h4* const qb = &SDL[(t & 3) * SDP + sdwOff];
        h4 c0 = dnp(sd0), c1 = dnp(sd1), c2 = dnp(sd2), c3 = dnp(sd3);
        *(h8*)qb       = __builtin_shufflevector(c0, c1, 0,1,2,3,4,5,6,7);
        *(h8*)(qb + 2) = __builtin_shufflevector(c2, c3, 0,1,2,3,4,5,6,7);
        qb[4 + (g & 1)] = dnp(sd4);
        // prefetch lead slice for t+2 (global slice d0-4+(t+2))
        pLIs = 0.f; pLJs = 0.f;
        const int sn = d0 - 2 + t;
        if (t + 2 < NIT && colOK && sn >= 0 && sn < DD) {
            pLIs = *(const v4*)(Ib + (size_t)sn * HWs);
            pLJs = *(const v4*)(Jb + (size_t)sn * HWs);
        }
        // prefetch retiring slice for t+2 (global slice d0-13+(t+2))
        pOIs = 0.f; pOJs = 0.f;
        const int so = d0 - 11 + t;
        if (t + 2 >= 9 && t + 2 < NIT && colOK && so >= 0) {
            pOIs = *(const v4*)(Ib + (size_t)so * HWs);
            pOJs = *(const v4*)(Jb + (size_t)so * HWs);
        }
    };

    auto PH2 = [&](int s) {
        const h4* const sdr = &SDL[(s & 3) * SDP + sdrOff];
        h4* const hsw = &HSL[(s & 3) * HSP + hswOff];
        h4 keep[7];                 // rows 0..6 of the initial window
        h4 sum = sdr[0];
        keep[0] = sum;
#pragma unroll
        for (int kk = 1; kk < 9; ++kk) {
            h4 v = sdr[kk * SDRS + (kk >= 8 ? 2 : 0)];
            if (kk < 7) keep[kk] = v;
            sum += v;
        }
        hsw[0] = sum;
#pragma unroll
        for (int j = 1; j < 8; ++j) {
            sum += sdr[(j + 8) * SDRS + 2] - keep[j - 1];
            hsw[j * HSRS] = sum;
        }
    };

    auto PH3 = [&](int s) {
        const h4* const hsr = &HSL[(s & 3) * HSP + hsrOff];
        float w[5][4];
#pragma unroll
        for (int c = 0; c < 5; ++c) {
            v4 fa = up(hsr[c * HSC]);
            v4 fb = up(hsr[c * HSC + 1]);
            v4 fc = up(hsr[c * HSC + 2]);
            float s0 = fa[0] + fa[1] + fa[2] + fa[3] +
                       fb[0] + fb[1] + fb[2] + fb[3] + fc[0];
            w[c][0] = s0;
            s0 += fc[1] - fa[0]; w[c][1] = s0;
            s0 += fc[2] - fa[1]; w[c][2] = s0;
            s0 += fc[3] - fa[2]; w[c][3] = s0;
        }
#pragma unroll
        for (int e = 0; e < 4; ++e) {
            float mu1 = w[0][e] * inv, mu2 = w[1][e] * inv;
            float g1  = fmaf(-mu1, mu1, w[2][e] * inv);
            float g2v = fmaf(-mu2, mu2, w[3][e] * inv);
            float g12 = fmaf(-mu1, mu2, w[4][e] * inv);
            acc += __fdividef(g12 * g12, fmaf(g1, g2v, 1e-5f));
        }
    };

#pragma unroll
    for (int k = 0; k < 16; ++k) {
        const int t0 = 2 * k, t1 = 2 * k + 1;
        if (t0 < NIT && p1) PH1(t0, pLI0, pLJ0, pOI0, pOJ0);
        if (t1 < NIT && p1) PH1(t1, pLI1, pLJ1, pOI1, pOJ1);
        if (k >= 1 && k <= 14 && p2) { PH2(2 * k - 2); PH2(2 * k - 1); }
        if (k >= 6 && p3)            { PH3(2 * k - 4); PH3(2 * k - 3); }
        block_sync_lds();
    }

    red[tid] = acc;     // only p3 threads have nonzero acc
    __syncthreads();
    if (tid < 128) red[tid] += red[tid + 128];
    __syncthreads();
    if (tid < 64) {
        float a = red[tid] + red[tid + 64];
#pragma unroll
        for (int off = 32; off > 0; off >>= 1) a += __shfl_down(a, off);
        if (tid == 0) partial[bid] = a;
    }
}

__global__ void k3_final(const float* __restrict__ partial,
                         float* __restrict__ out) {
    __shared__ float r[1024];
    const int i = threadIdx.x;
    r[i] = (i < NBLK) ? partial[i] : 0.f;
    __syncthreads();
    for (int off = 512; off > 0; off >>= 1) {
        if (i < off) r[i] += r[i + off];
        __syncthreads();
    }
    if (i == 0) out[0] = -r[0] * (1.0f / NTOT);
}

extern "C" void kernel_launch(void* const* d_in, const int* in_sizes, int n_in,
                              void* d_out, int out_size, void* d_ws, size_t ws_size,
                              hipStream_t stream) {
    (void)in_sizes; (void)n_in; (void)out_size; (void)ws_size;
    const float* I = (const float*)d_in[0];   // y_true
    const float* J = (const float*)d_in[1];   // y_pred
    float* out     = (float*)d_out;
    float* partial = (float*)d_ws;            // NBLK floats, all written

    kf<<<dim3(NBLK), 256, 0, stream>>>(I, J, partial);
    k3_final<<<1, 1024, 0, stream>>>(partial, out);
}